// Round 10
// baseline (727.273 us; speedup 1.0000x reference)
//
#include <hip/hip_runtime.h>
#include <math.h>

// SVPF step: B=8, N=2048, D=4, fp32.  3 SVGD iterations.
// log_weight output channel is exactly -log(2048) (log_post cancels).
//
// R10 changes vs R9 (diagnosis: R9's ping-pong ARRAYS bx[2][4]/bg[2][4] were
// spilled to scratch -> 300MB HBM traffic/dispatch, occupancy 0.3%; rule:
// register pipelines need NAMED variables, never indexed arrays):
//  - revert to R7 structure (known 328us), then: stein/grad j-loops use a
//    macro-unrolled 3-buffer rotation with individually NAMED float4 vars
//    (A/B/C sets; 16 chunks of 128 j).  Chunk c computes while c+1,c+2
//    loads are in flight (~2 chunk-computes of slack ~ L2 latency).
//  - buffer footprint budgeted: stein 48 VGPR, grad 24 VGPR -> total ~100,
//    under the 128 cap of __launch_bounds__(256,4).  No arrays -> no scratch.
//  - hist/scan/init and the 10-launch structure unchanged from R7.
//
// ws layout (floats):
//   xA[65536] xB[65536] g[65536] step[65536] ap[65536]
//   state[16 ints] hist0[8*2048 ints] hist1[8*4096 ints]

#define NPART 2048
#define KRANK 2097151               // (2048*2048-1)/2, lower-median rank
#define LOGN_F 7.6246189861593985f  // log(2048)
#define A_C 0.9f

// ---------- init: x0 = A*prev + noise; ap = A*prev; zero hist0+hist1
__global__ __launch_bounds__(256) void k_init(const float* __restrict__ prev,
                                              const float* __restrict__ noise,
                                              float* __restrict__ x0,
                                              float* __restrict__ apb,
                                              int* __restrict__ hists) {
  int idx = blockIdx.x * 256 + threadIdx.x;   // 0..16383 (B*N)
  float4 p  = ((const float4*)prev)[idx];
  float4 nz = ((const float4*)noise)[idx];
  float4 ap = make_float4(A_C*p.x, A_C*p.y, A_C*p.z, A_C*p.w);
  ((float4*)x0)[idx]  = make_float4(ap.x+nz.x, ap.y+nz.y, ap.z+nz.z, ap.w+nz.w);
  ((float4*)apb)[idx] = ap;
  if (idx < 12288) ((int4*)hists)[idx] = make_int4(0, 0, 0, 0);  // 49152 ints
}

// ---- per-pair helpers (all register, compile-time indexed) ----
__device__ __forceinline__ void grad_j(const float4* xi, const float4 ap,
                                       float* s, float4* acc) {
#pragma unroll
  for (int r = 0; r < 4; ++r) {
    float dx = xi[r].x - ap.x, dy = xi[r].y - ap.y;
    float dz = xi[r].z - ap.z, dw = xi[r].w - ap.w;
    float sq = fmaf(dx, dx, fmaf(dy, dy, fmaf(dz, dz, dw*dw)));
    float e = __expf(-0.5f * sq);
    s[r] += e;
    acc[r].x = fmaf(e, ap.x, acc[r].x);
    acc[r].y = fmaf(e, ap.y, acc[r].y);
    acc[r].z = fmaf(e, ap.z, acc[r].z);
    acc[r].w = fmaf(e, ap.w, acc[r].w);
  }
}

__device__ __forceinline__ void stein_j(const float4* xi, const float4 xj,
                                        const float4 gj, float two_h,
                                        float ninvh, float* s0, float4* sc) {
  float4 cj;   // g_j - (2/h) x_j, shared across the 4 rows
  cj.x = fmaf(-two_h, xj.x, gj.x);
  cj.y = fmaf(-two_h, xj.y, gj.y);
  cj.z = fmaf(-two_h, xj.z, gj.z);
  cj.w = fmaf(-two_h, xj.w, gj.w);
#pragma unroll
  for (int r = 0; r < 4; ++r) {
    float dx = xi[r].x - xj.x, dy = xi[r].y - xj.y;
    float dz = xi[r].z - xj.z, dw = xi[r].w - xj.w;
    float sq = fmaf(dx, dx, fmaf(dy, dy, fmaf(dz, dz, dw*dw)));
    float e = __expf(sq * ninvh);
    s0[r] += e;
    sc[r].x = fmaf(e, cj.x, sc[r].x);
    sc[r].y = fmaf(e, cj.y, sc[r].y);
    sc[r].z = fmaf(e, cj.z, sc[r].z);
    sc[r].w = fmaf(e, cj.w, sc[r].w);
  }
}

// ---- grad pipeline macros: chunk c = j in [c*128, (c+1)*128), 2 j/lane ----
#define GLOAD(P0, P1, c) \
  P0 = ab[lane + (c)*128]; P1 = ab[lane + 64 + (c)*128];
#define GCOMP(P0, P1) \
  grad_j(xi, P0, sum, acc); grad_j(xi, P1, sum, acc);

// ---- stein pipeline macros ----
#define SLOAD(X0, X1, G0, G1, c) \
  X0 = xb[lane + (c)*128]; X1 = xb[lane + 64 + (c)*128]; \
  G0 = gb[lane + (c)*128]; G1 = gb[lane + 64 + (c)*128];
#define SCOMP(X0, X1, G0, G1) \
  stein_j(xi, X0, G0, two_h, neginvh, S0, Sc); \
  stein_j(xi, X1, G1, two_h, neginvh, S0, Sc);

// ---------- S1: role = blockIdx&1.  role 0: grad (1024 blocks, 16 rows ea).
// role 1: hist0 (1024 blocks).  Also zeroes hist1.
__global__ __launch_bounds__(256, 4) void k_s1(const float* __restrict__ x,
                                               const float* __restrict__ apb,
                                               const float* __restrict__ obs,
                                               float* __restrict__ g,
                                               int* __restrict__ hist0,
                                               int* __restrict__ hist1) {
  if (threadIdx.x < 4)
    ((int4*)hist1)[blockIdx.x*4 + threadIdx.x] = make_int4(0, 0, 0, 0);
  int role = blockIdx.x & 1;
  int id   = blockIdx.x >> 1;

  if (role == 0) {
    // ---- grad: wave (64 lanes) serves 4 rows; block = 16 rows ----
    int b = id >> 7;                        // 128 blocks/batch
    int rbase = (id & 127)*16 + (threadIdx.x >> 6)*4;
    int lane = threadIdx.x & 63;
    const float4* xb = (const float4*)x + b*NPART;
    const float4* ab = (const float4*)apb + b*NPART;
    float4 xi[4];
#pragma unroll
    for (int r = 0; r < 4; ++r) xi[r] = xb[rbase + r];
    float  sum[4] = {0.f, 0.f, 0.f, 0.f};
    float4 acc[4] = {{0,0,0,0},{0,0,0,0},{0,0,0,0},{0,0,0,0}};

    // 3-buffer named rotation, 16 chunks of 128 j
    float4 pA0, pA1, pB0, pB1, pC0, pC1;
    GLOAD(pA0, pA1, 0)
    GLOAD(pB0, pB1, 1)
    GLOAD(pC0, pC1, 2)
    GCOMP(pA0, pA1) GLOAD(pA0, pA1, 3)
    GCOMP(pB0, pB1) GLOAD(pB0, pB1, 4)
    GCOMP(pC0, pC1) GLOAD(pC0, pC1, 5)
    GCOMP(pA0, pA1) GLOAD(pA0, pA1, 6)
    GCOMP(pB0, pB1) GLOAD(pB0, pB1, 7)
    GCOMP(pC0, pC1) GLOAD(pC0, pC1, 8)
    GCOMP(pA0, pA1) GLOAD(pA0, pA1, 9)
    GCOMP(pB0, pB1) GLOAD(pB0, pB1, 10)
    GCOMP(pC0, pC1) GLOAD(pC0, pC1, 11)
    GCOMP(pA0, pA1) GLOAD(pA0, pA1, 12)
    GCOMP(pB0, pB1) GLOAD(pB0, pB1, 13)
    GCOMP(pC0, pC1) GLOAD(pC0, pC1, 14)
    GCOMP(pA0, pA1) GLOAD(pA0, pA1, 15)
    GCOMP(pB0, pB1)
    GCOMP(pC0, pC1)
    GCOMP(pA0, pA1)

#pragma unroll
    for (int d = 1; d < 64; d <<= 1) {
#pragma unroll
      for (int r = 0; r < 4; ++r) {
        sum[r]   += __shfl_xor(sum[r], d);
        acc[r].x += __shfl_xor(acc[r].x, d);
        acc[r].y += __shfl_xor(acc[r].y, d);
        acc[r].z += __shfl_xor(acc[r].z, d);
        acc[r].w += __shfl_xor(acc[r].w, d);
      }
    }
    if (lane == 0) {
      float4 ob = ((const float4*)obs)[b];
#pragma unroll
      for (int r = 0; r < 4; ++r) {
        float inv = 1.0f / sum[r];
        float4 gg;
        gg.x = fmaf(acc[r].x, inv, fmaf(-2.0f, xi[r].x, ob.x));
        gg.y = fmaf(acc[r].y, inv, fmaf(-2.0f, xi[r].y, ob.y));
        gg.z = fmaf(acc[r].z, inv, fmaf(-2.0f, xi[r].z, ob.z));
        gg.w = fmaf(acc[r].w, inv, fmaf(-2.0f, xi[r].w, ob.w));
        ((float4*)g)[b*NPART + rbase + r] = gg;
      }
    }
  } else {
    // ---- hist0: LDS-staged, 2-copy histogram ----
    int b     = id >> 7;
    int sub2  = id & 127;
    int itile = sub2 >> 4;            // 8 i-tiles of 256
    int ktile = sub2 & 15;            // 16 k-tiles of 64
    __shared__ float4 sxi[256];
    __shared__ float4 sxw[320];
    __shared__ int    sh[2*2049];

    const float4* xb = (const float4*)x + b*NPART;
    int ibase = itile*256;
    int k0 = ktile*64 + 1;
    sxi[threadIdx.x] = xb[ibase + threadIdx.x];
    for (int t = threadIdx.x; t < 320; t += 256)
      sxw[t] = xb[(ibase + k0 + t) & (NPART - 1)];
    for (int t = threadIdx.x; t < 2*2049; t += 256) sh[t] = 0;
    __syncthreads();

    float4 xi = sxi[threadIdx.x];
    int cofs = (threadIdx.x & 1) * 2049;
#pragma unroll 4
    for (int kk = 0; kk < 64; ++kk) {
      int w = (ktile == 15 && kk == 63) ? 1 : 2;   // wave-uniform
      float4 xj = sxw[threadIdx.x + kk];
      float dx = xi.x - xj.x, dy = xi.y - xj.y;
      float dz = xi.z - xj.z, dw = xi.w - xj.w;
      float sq = dx*dx + dy*dy + dz*dz + dw*dw;    // >= 0
      atomicAdd(&sh[cofs + (__float_as_uint(sq) >> 20)], w);
    }
    __syncthreads();
    int* hb = hist0 + b*2048;
    for (int t = threadIdx.x; t < 2048; t += 256) {
      int c = sh[t] + sh[t + 2049];
      if (c) atomicAdd(&hb[t], c);
    }
  }
}

// ---------- S2: self-scan of hist0 (phase-0 rank walk) + hist1 accumulation.
__global__ __launch_bounds__(256) void k_s2(const float* __restrict__ x,
                                            int* __restrict__ state,
                                            const int* __restrict__ hist0,
                                            int* __restrict__ hist1) {
  int b     = blockIdx.x >> 7;
  int sub2  = blockIdx.x & 127;
  int itile = sub2 >> 4;
  int ktile = sub2 & 15;
  __shared__ float4 sxi[256];
  __shared__ float4 sxw[320];
  __shared__ int    sh[4096];
  __shared__ int    part[256];
  __shared__ int    s_sel0;

  const float4* xb = (const float4*)x + b*NPART;
  int ibase = itile*256;
  int k0 = ktile*64 + 1;
  sxi[threadIdx.x] = xb[ibase + threadIdx.x];
  for (int t = threadIdx.x; t < 320; t += 256)
    sxw[t] = xb[(ibase + k0 + t) & (NPART - 1)];
  for (int t = threadIdx.x; t < 4096; t += 256) sh[t] = 0;

  const int* h0 = hist0 + b*2048;
  int4 c0 = ((const int4*)h0)[threadIdx.x*2];
  int4 c1 = ((const int4*)h0)[threadIdx.x*2 + 1];
  int s = c0.x+c0.y+c0.z+c0.w + c1.x+c1.y+c1.z+c1.w;
  if (threadIdx.x == 0) s += NPART;   // diagonal zeros -> bin 0
  part[threadIdx.x] = s;
  __syncthreads();
  if (threadIdx.x == 0) {
    int r = KRANK, cum = 0, ch = 0;
    for (; ch < 256; ++ch) { if (cum + part[ch] > r) break; cum += part[ch]; }
    int4 d0 = ((const int4*)h0)[ch*2];
    int4 d1 = ((const int4*)h0)[ch*2 + 1];
    int cc[8] = {d0.x,d0.y,d0.z,d0.w,d1.x,d1.y,d1.z,d1.w};
    if (ch == 0) cc[0] += NPART;
    int q = 0;
    for (;; ++q) { if (cum + cc[q] > r) break; cum += cc[q]; }
    int bin = ch*8 + q;
    s_sel0 = bin;
    if (sub2 == 0) { state[b*2] = bin; state[b*2 + 1] = r - cum; }
  }
  __syncthreads();
  int sel0 = s_sel0;

  float4 xi = sxi[threadIdx.x];
#pragma unroll 4
  for (int kk = 0; kk < 64; ++kk) {
    int w = (ktile == 15 && kk == 63) ? 1 : 2;
    float4 xj = sxw[threadIdx.x + kk];
    float dx = xi.x - xj.x, dy = xi.y - xj.y;
    float dz = xi.z - xj.z, dw = xi.w - xj.w;
    float sq = dx*dx + dy*dy + dz*dz + dw*dw;
    unsigned bits = __float_as_uint(sq);
    if ((int)(bits >> 20) == sel0) atomicAdd(&sh[(bits >> 8) & 4095], w);
  }
  __syncthreads();
  int* hb = hist1 + b*4096;
  for (int t = threadIdx.x; t < 4096; t += 256) {
    int c = sh[t];
    if (c) atomicAdd(&hb[t], c);
  }
}

// ---------- S3: zero hist0; self-scan hist1 -> h; stein + RMSprop.
// 1024 blocks, 16 rows each; wave (64 lanes) serves 4 rows.
// MODE 0: first iter.  MODE 1: middle.  MODE 2: last (writes (B,N,5) out).
template <int MODE>
__global__ __launch_bounds__(256, 4) void k_s3(const float* __restrict__ x,
                                               const float* __restrict__ g,
                                               const int* __restrict__ state,
                                               int* __restrict__ hist0,
                                               const int* __restrict__ hist1,
                                               float* __restrict__ stepb,
                                               float* __restrict__ xout,
                                               float* __restrict__ outp) {
  // zero hist0 (last read by S2, a previous kernel)
  if (threadIdx.x < 4)
    ((int4*)hist0)[blockIdx.x*4 + threadIdx.x] = make_int4(0, 0, 0, 0);

  int b = blockIdx.x >> 7;            // 128 blocks/batch
  __shared__ int   part[256];
  __shared__ float shp[2];            // -1/h, 2/h

  const int* h1 = hist1 + b*4096;
  int4 c0 = ((const int4*)h1)[threadIdx.x*4 + 0];
  int4 c1 = ((const int4*)h1)[threadIdx.x*4 + 1];
  int4 c2 = ((const int4*)h1)[threadIdx.x*4 + 2];
  int4 c3 = ((const int4*)h1)[threadIdx.x*4 + 3];
  int s = c0.x+c0.y+c0.z+c0.w + c1.x+c1.y+c1.z+c1.w
        + c2.x+c2.y+c2.z+c2.w + c3.x+c3.y+c3.z+c3.w;
  int sel0 = state[b*2];
  if (threadIdx.x == 0 && sel0 == 0) s += NPART;
  part[threadIdx.x] = s;
  __syncthreads();
  if (threadIdx.x == 0) {
    int r = state[b*2 + 1], cum = 0, ch = 0;
    for (; ch < 256; ++ch) { if (cum + part[ch] > r) break; cum += part[ch]; }
    int4 d0 = ((const int4*)h1)[ch*4 + 0];
    int4 d1 = ((const int4*)h1)[ch*4 + 1];
    int4 d2 = ((const int4*)h1)[ch*4 + 2];
    int4 d3 = ((const int4*)h1)[ch*4 + 3];
    int cc[16] = {d0.x,d0.y,d0.z,d0.w, d1.x,d1.y,d1.z,d1.w,
                  d2.x,d2.y,d2.z,d2.w, d3.x,d3.y,d3.z,d3.w};
    if (sel0 == 0 && ch == 0) cc[0] += NPART;
    int q = 0;
    for (;; ++q) { if (cum + cc[q] > r) break; cum += cc[q]; }
    int bin = ch*16 + q;
    // top 24 bits exact; low 8 -> midpoint (rel err <= 2^-16)
    unsigned mb = (((unsigned)sel0) << 20) | (((unsigned)bin) << 8) | 128u;
    float med = sqrtf(__uint_as_float(mb));
    float h = med * med / LOGN_F;
    shp[0] = -1.0f / h;
    shp[1] =  2.0f / h;
  }
  __syncthreads();
  float neginvh = shp[0];
  float two_h   = shp[1];

  int rbase = (blockIdx.x & 127)*16 + (threadIdx.x >> 6)*4;
  int lane = threadIdx.x & 63;
  const float4* xb = (const float4*)x + b*NPART;
  const float4* gb = (const float4*)g + b*NPART;
  float4 xi[4];
#pragma unroll
  for (int r = 0; r < 4; ++r) xi[r] = xb[rbase + r];
  float  S0[4] = {0.f, 0.f, 0.f, 0.f};
  float4 Sc[4] = {{0,0,0,0},{0,0,0,0},{0,0,0,0},{0,0,0,0}};

  // 3-buffer named rotation, 16 chunks of 128 j
  float4 sxA0, sxA1, sgA0, sgA1;
  float4 sxB0, sxB1, sgB0, sgB1;
  float4 sxC0, sxC1, sgC0, sgC1;
  SLOAD(sxA0, sxA1, sgA0, sgA1, 0)
  SLOAD(sxB0, sxB1, sgB0, sgB1, 1)
  SLOAD(sxC0, sxC1, sgC0, sgC1, 2)
  SCOMP(sxA0, sxA1, sgA0, sgA1) SLOAD(sxA0, sxA1, sgA0, sgA1, 3)
  SCOMP(sxB0, sxB1, sgB0, sgB1) SLOAD(sxB0, sxB1, sgB0, sgB1, 4)
  SCOMP(sxC0, sxC1, sgC0, sgC1) SLOAD(sxC0, sxC1, sgC0, sgC1, 5)
  SCOMP(sxA0, sxA1, sgA0, sgA1) SLOAD(sxA0, sxA1, sgA0, sgA1, 6)
  SCOMP(sxB0, sxB1, sgB0, sgB1) SLOAD(sxB0, sxB1, sgB0, sgB1, 7)
  SCOMP(sxC0, sxC1, sgC0, sgC1) SLOAD(sxC0, sxC1, sgC0, sgC1, 8)
  SCOMP(sxA0, sxA1, sgA0, sgA1) SLOAD(sxA0, sxA1, sgA0, sgA1, 9)
  SCOMP(sxB0, sxB1, sgB0, sgB1) SLOAD(sxB0, sxB1, sgB0, sgB1, 10)
  SCOMP(sxC0, sxC1, sgC0, sgC1) SLOAD(sxC0, sxC1, sgC0, sgC1, 11)
  SCOMP(sxA0, sxA1, sgA0, sgA1) SLOAD(sxA0, sxA1, sgA0, sgA1, 12)
  SCOMP(sxB0, sxB1, sgB0, sgB1) SLOAD(sxB0, sxB1, sgB0, sgB1, 13)
  SCOMP(sxC0, sxC1, sgC0, sgC1) SLOAD(sxC0, sxC1, sgC0, sgC1, 14)
  SCOMP(sxA0, sxA1, sgA0, sgA1) SLOAD(sxA0, sxA1, sgA0, sgA1, 15)
  SCOMP(sxB0, sxB1, sgB0, sgB1)
  SCOMP(sxC0, sxC1, sgC0, sgC1)
  SCOMP(sxA0, sxA1, sgA0, sgA1)

#pragma unroll
  for (int d = 1; d < 64; d <<= 1) {
#pragma unroll
    for (int r = 0; r < 4; ++r) {
      S0[r]   += __shfl_xor(S0[r], d);
      Sc[r].x += __shfl_xor(Sc[r].x, d);
      Sc[r].y += __shfl_xor(Sc[r].y, d);
      Sc[r].z += __shfl_xor(Sc[r].z, d);
      Sc[r].w += __shfl_xor(Sc[r].w, d);
    }
  }
  if (lane == 0) {
    const float invN = 1.0f / 2048.0f;
#pragma unroll
    for (int r = 0; r < 4; ++r) {
      int row = rbase + r;
      float th0 = two_h * S0[r];
      float4 sv;
      sv.x = fmaf(th0, xi[r].x, Sc[r].x) * invN;
      sv.y = fmaf(th0, xi[r].y, Sc[r].y) * invN;
      sv.z = fmaf(th0, xi[r].z, Sc[r].z) * invN;
      sv.w = fmaf(th0, xi[r].w, Sc[r].w) * invN;
      float4 st;
      if (MODE == 0) {
        st = make_float4(0.1f*sv.x*sv.x, 0.1f*sv.y*sv.y,
                         0.1f*sv.z*sv.z, 0.1f*sv.w*sv.w);
      } else {
        st = ((float4*)stepb)[b*NPART + row];
        st.x = 0.9f*st.x + 0.1f*sv.x*sv.x;
        st.y = 0.9f*st.y + 0.1f*sv.y*sv.y;
        st.z = 0.9f*st.z + 0.1f*sv.z*sv.z;
        st.w = 0.9f*st.w + 0.1f*sv.w*sv.w;
      }
      float4 xn;
      xn.x = xi[r].x + 0.1f*sv.x / (sqrtf(st.x) + 1e-8f);
      xn.y = xi[r].y + 0.1f*sv.y / (sqrtf(st.y) + 1e-8f);
      xn.z = xi[r].z + 0.1f*sv.z / (sqrtf(st.z) + 1e-8f);
      xn.w = xi[r].w + 0.1f*sv.w / (sqrtf(st.w) + 1e-8f);
      if (MODE != 2) {
        ((float4*)stepb)[b*NPART + row] = st;
        ((float4*)xout)[b*NPART + row] = xn;
      } else {
        float* o = outp + (size_t)(b*NPART + row) * 5;
        o[0] = xn.x; o[1] = xn.y; o[2] = xn.z; o[3] = xn.w;
        o[4] = -LOGN_F;
      }
    }
  }
}

extern "C" void kernel_launch(void* const* d_in, const int* in_sizes, int n_in,
                              void* d_out, int out_size, void* d_ws, size_t ws_size,
                              hipStream_t stream) {
  const float* prev  = (const float*)d_in[0];   // (8,2048,4)
  const float* obs   = (const float*)d_in[1];   // (8,4)
  const float* noise = (const float*)d_in[2];   // (8,2048,4)
  float* out = (float*)d_out;                   // (8,2048,5)

  float* ws = (float*)d_ws;
  float* xA    = ws;
  float* xB    = xA + 65536;
  float* gbuf  = xB + 65536;
  float* stepb = gbuf + 65536;
  float* apb   = stepb + 65536;
  int*   state = (int*)(apb + 65536);       // 16 ints
  int*   hist0 = state + 16;                // 8*2048 ints
  int*   hist1 = hist0 + 8*2048;            // 8*4096 ints

  k_init<<<64, 256, 0, stream>>>(prev, noise, xA, apb, hist0);

  float* xc = xA;
  float* xn = xB;
  for (int it = 0; it < 3; ++it) {
    k_s1<<<2048, 256, 0, stream>>>(xc, apb, obs, gbuf, hist0, hist1);
    k_s2<<<1024, 256, 0, stream>>>(xc, state, hist0, hist1);
    if (it == 0) {
      k_s3<0><<<1024, 256, 0, stream>>>(xc, gbuf, state, hist0, hist1, stepb, xn, nullptr);
    } else if (it == 1) {
      k_s3<1><<<1024, 256, 0, stream>>>(xc, gbuf, state, hist0, hist1, stepb, xn, nullptr);
    } else {
      k_s3<2><<<1024, 256, 0, stream>>>(xc, gbuf, state, hist0, hist1, stepb, nullptr, out);
    }
    float* t = xc; xc = xn; xn = t;
  }
}

// Round 11
// 347.512 us; speedup vs baseline: 2.0928x; 2.0928x over previous
//
#include <hip/hip_runtime.h>
#include <math.h>

// SVPF step: B=8, N=2048, D=4, fp32.  3 SVGD iterations.
// log_weight output channel is exactly -log(2048) (log_post cancels).
//
// R11 changes vs R10 (diagnosis: TWO consecutive register-pipeline attempts
// spilled to scratch (FETCH 133MB/WRITE 253MB, VGPR pinned at 64 under
// __launch_bounds__(256,4)) -> stop fighting the allocator; hide latency in
// LDS where register demand stays ~75):
//  - grad & stein j-loops: double-buffered LDS tiles (T14 async-stage):
//    issue tile t+1 global loads into 2-4 NAMED regs, compute tile t from
//    LDS, sync, write regs->LDS, sync.  Stein: 4 tiles x 512 j staging
//    {x_j, c_j = g_j - (2/h)x_j} (32 KB).  Grad: 8 tiles x 256 j of ap_j
//    (8 KB).
//  - plain __launch_bounds__(256) on s1/s3 (the (256,4) variant correlated
//    with the 64-reg pin + spill).
//  - hist/scan/init and the 10-launch structure unchanged from R7.
//
// ws layout (floats):
//   xA[65536] xB[65536] g[65536] step[65536] ap[65536]
//   state[16 ints] hist0[8*2048 ints] hist1[8*4096 ints]

#define NPART 2048
#define KRANK 2097151               // (2048*2048-1)/2, lower-median rank
#define LOGN_F 7.6246189861593985f  // log(2048)
#define A_C 0.9f

// ---------- init: x0 = A*prev + noise; ap = A*prev; zero hist0+hist1
__global__ __launch_bounds__(256) void k_init(const float* __restrict__ prev,
                                              const float* __restrict__ noise,
                                              float* __restrict__ x0,
                                              float* __restrict__ apb,
                                              int* __restrict__ hists) {
  int idx = blockIdx.x * 256 + threadIdx.x;   // 0..16383 (B*N)
  float4 p  = ((const float4*)prev)[idx];
  float4 nz = ((const float4*)noise)[idx];
  float4 ap = make_float4(A_C*p.x, A_C*p.y, A_C*p.z, A_C*p.w);
  ((float4*)x0)[idx]  = make_float4(ap.x+nz.x, ap.y+nz.y, ap.z+nz.z, ap.w+nz.w);
  ((float4*)apb)[idx] = ap;
  if (idx < 12288) ((int4*)hists)[idx] = make_int4(0, 0, 0, 0);  // 49152 ints
}

// ---------- S1: role = blockIdx&1.  role 0: grad (1024 blocks, 16 rows ea).
// role 1: hist0 (1024 blocks).  Also zeroes hist1.
__global__ __launch_bounds__(256) void k_s1(const float* __restrict__ x,
                                            const float* __restrict__ apb,
                                            const float* __restrict__ obs,
                                            float* __restrict__ g,
                                            int* __restrict__ hist0,
                                            int* __restrict__ hist1) {
  if (threadIdx.x < 4)
    ((int4*)hist1)[blockIdx.x*4 + threadIdx.x] = make_int4(0, 0, 0, 0);
  int role = blockIdx.x & 1;
  int id   = blockIdx.x >> 1;

  if (role == 0) {
    // ---- grad: wave (64 lanes) serves 4 rows; block = 16 rows.
    // j-stream staged in double-buffered LDS tiles of 256 (8 tiles).
    __shared__ float4 sap[2][256];
    int b = id >> 7;                        // 128 blocks/batch
    int rbase = (id & 127)*16 + (threadIdx.x >> 6)*4;
    int lane = threadIdx.x & 63;
    const float4* xb = (const float4*)x + b*NPART;
    const float4* ab = (const float4*)apb + b*NPART;
    float4 xi[4];
#pragma unroll
    for (int r = 0; r < 4; ++r) xi[r] = xb[rbase + r];
    float  sum[4] = {0.f, 0.f, 0.f, 0.f};
    float4 acc[4] = {{0,0,0,0},{0,0,0,0},{0,0,0,0},{0,0,0,0}};

    sap[0][threadIdx.x] = ab[threadIdx.x];   // stage tile 0
    __syncthreads();
    for (int t = 0; t < 8; ++t) {
      int cur = t & 1, nxt = cur ^ 1;
      float4 na;
      if (t < 7) na = ab[(t + 1)*256 + threadIdx.x];  // prefetch (hidden)
#pragma unroll
      for (int q = 0; q < 4; ++q) {
        float4 ap = sap[cur][lane + 64*q];
#pragma unroll
        for (int r = 0; r < 4; ++r) {
          float dx = xi[r].x - ap.x, dy = xi[r].y - ap.y;
          float dz = xi[r].z - ap.z, dw = xi[r].w - ap.w;
          float sq = fmaf(dx, dx, fmaf(dy, dy, fmaf(dz, dz, dw*dw)));
          float e = __expf(-0.5f * sq);
          sum[r] += e;
          acc[r].x = fmaf(e, ap.x, acc[r].x);
          acc[r].y = fmaf(e, ap.y, acc[r].y);
          acc[r].z = fmaf(e, ap.z, acc[r].z);
          acc[r].w = fmaf(e, ap.w, acc[r].w);
        }
      }
      __syncthreads();
      if (t < 7) {
        sap[nxt][threadIdx.x] = na;
        __syncthreads();
      }
    }
#pragma unroll
    for (int d = 1; d < 64; d <<= 1) {
#pragma unroll
      for (int r = 0; r < 4; ++r) {
        sum[r]   += __shfl_xor(sum[r], d);
        acc[r].x += __shfl_xor(acc[r].x, d);
        acc[r].y += __shfl_xor(acc[r].y, d);
        acc[r].z += __shfl_xor(acc[r].z, d);
        acc[r].w += __shfl_xor(acc[r].w, d);
      }
    }
    if (lane == 0) {
      float4 ob = ((const float4*)obs)[b];
#pragma unroll
      for (int r = 0; r < 4; ++r) {
        float inv = 1.0f / sum[r];
        float4 gg;
        gg.x = fmaf(acc[r].x, inv, fmaf(-2.0f, xi[r].x, ob.x));
        gg.y = fmaf(acc[r].y, inv, fmaf(-2.0f, xi[r].y, ob.y));
        gg.z = fmaf(acc[r].z, inv, fmaf(-2.0f, xi[r].z, ob.z));
        gg.w = fmaf(acc[r].w, inv, fmaf(-2.0f, xi[r].w, ob.w));
        ((float4*)g)[b*NPART + rbase + r] = gg;
      }
    }
  } else {
    // ---- hist0: LDS-staged, 2-copy histogram (unchanged) ----
    int b     = id >> 7;
    int sub2  = id & 127;
    int itile = sub2 >> 4;            // 8 i-tiles of 256
    int ktile = sub2 & 15;            // 16 k-tiles of 64
    __shared__ float4 sxi[256];
    __shared__ float4 sxw[320];
    __shared__ int    sh[2*2049];

    const float4* xb = (const float4*)x + b*NPART;
    int ibase = itile*256;
    int k0 = ktile*64 + 1;
    sxi[threadIdx.x] = xb[ibase + threadIdx.x];
    for (int t = threadIdx.x; t < 320; t += 256)
      sxw[t] = xb[(ibase + k0 + t) & (NPART - 1)];
    for (int t = threadIdx.x; t < 2*2049; t += 256) sh[t] = 0;
    __syncthreads();

    float4 xi = sxi[threadIdx.x];
    int cofs = (threadIdx.x & 1) * 2049;
#pragma unroll 4
    for (int kk = 0; kk < 64; ++kk) {
      int w = (ktile == 15 && kk == 63) ? 1 : 2;   // wave-uniform
      float4 xj = sxw[threadIdx.x + kk];
      float dx = xi.x - xj.x, dy = xi.y - xj.y;
      float dz = xi.z - xj.z, dw = xi.w - xj.w;
      float sq = dx*dx + dy*dy + dz*dz + dw*dw;    // >= 0
      atomicAdd(&sh[cofs + (__float_as_uint(sq) >> 20)], w);
    }
    __syncthreads();
    int* hb = hist0 + b*2048;
    for (int t = threadIdx.x; t < 2048; t += 256) {
      int c = sh[t] + sh[t + 2049];
      if (c) atomicAdd(&hb[t], c);
    }
  }
}

// ---------- S2: self-scan of hist0 (phase-0 rank walk) + hist1 accumulation.
__global__ __launch_bounds__(256) void k_s2(const float* __restrict__ x,
                                            int* __restrict__ state,
                                            const int* __restrict__ hist0,
                                            int* __restrict__ hist1) {
  int b     = blockIdx.x >> 7;
  int sub2  = blockIdx.x & 127;
  int itile = sub2 >> 4;
  int ktile = sub2 & 15;
  __shared__ float4 sxi[256];
  __shared__ float4 sxw[320];
  __shared__ int    sh[4096];
  __shared__ int    part[256];
  __shared__ int    s_sel0;

  const float4* xb = (const float4*)x + b*NPART;
  int ibase = itile*256;
  int k0 = ktile*64 + 1;
  sxi[threadIdx.x] = xb[ibase + threadIdx.x];
  for (int t = threadIdx.x; t < 320; t += 256)
    sxw[t] = xb[(ibase + k0 + t) & (NPART - 1)];
  for (int t = threadIdx.x; t < 4096; t += 256) sh[t] = 0;

  const int* h0 = hist0 + b*2048;
  int4 c0 = ((const int4*)h0)[threadIdx.x*2];
  int4 c1 = ((const int4*)h0)[threadIdx.x*2 + 1];
  int s = c0.x+c0.y+c0.z+c0.w + c1.x+c1.y+c1.z+c1.w;
  if (threadIdx.x == 0) s += NPART;   // diagonal zeros -> bin 0
  part[threadIdx.x] = s;
  __syncthreads();
  if (threadIdx.x == 0) {
    int r = KRANK, cum = 0, ch = 0;
    for (; ch < 256; ++ch) { if (cum + part[ch] > r) break; cum += part[ch]; }
    int4 d0 = ((const int4*)h0)[ch*2];
    int4 d1 = ((const int4*)h0)[ch*2 + 1];
    int cc[8] = {d0.x,d0.y,d0.z,d0.w,d1.x,d1.y,d1.z,d1.w};
    if (ch == 0) cc[0] += NPART;
    int q = 0;
    for (;; ++q) { if (cum + cc[q] > r) break; cum += cc[q]; }
    int bin = ch*8 + q;
    s_sel0 = bin;
    if (sub2 == 0) { state[b*2] = bin; state[b*2 + 1] = r - cum; }
  }
  __syncthreads();
  int sel0 = s_sel0;

  float4 xi = sxi[threadIdx.x];
#pragma unroll 4
  for (int kk = 0; kk < 64; ++kk) {
    int w = (ktile == 15 && kk == 63) ? 1 : 2;
    float4 xj = sxw[threadIdx.x + kk];
    float dx = xi.x - xj.x, dy = xi.y - xj.y;
    float dz = xi.z - xj.z, dw = xi.w - xj.w;
    float sq = dx*dx + dy*dy + dz*dz + dw*dw;
    unsigned bits = __float_as_uint(sq);
    if ((int)(bits >> 20) == sel0) atomicAdd(&sh[(bits >> 8) & 4095], w);
  }
  __syncthreads();
  int* hb = hist1 + b*4096;
  for (int t = threadIdx.x; t < 4096; t += 256) {
    int c = sh[t];
    if (c) atomicAdd(&hb[t], c);
  }
}

// ---------- S3: zero hist0; self-scan hist1 -> h; stein + RMSprop.
// 1024 blocks, 16 rows each; wave (64 lanes) serves 4 rows.
// j-stream staged in double-buffered LDS tiles of 512 (4 tiles):
//   {x_j, c_j = g_j - (2/h) x_j}.
// MODE 0: first iter.  MODE 1: middle.  MODE 2: last (writes (B,N,5) out).
template <int MODE>
__global__ __launch_bounds__(256) void k_s3(const float* __restrict__ x,
                                            const float* __restrict__ g,
                                            const int* __restrict__ state,
                                            int* __restrict__ hist0,
                                            const int* __restrict__ hist1,
                                            float* __restrict__ stepb,
                                            float* __restrict__ xout,
                                            float* __restrict__ outp) {
  // zero hist0 (last read by S2, a previous kernel)
  if (threadIdx.x < 4)
    ((int4*)hist0)[blockIdx.x*4 + threadIdx.x] = make_int4(0, 0, 0, 0);

  int b = blockIdx.x >> 7;            // 128 blocks/batch
  __shared__ int    part[256];
  __shared__ float  shp[2];           // -1/h, 2/h
  __shared__ float4 sx[2][512];       // 16 KB
  __shared__ float4 sc[2][512];       // 16 KB

  const int* h1 = hist1 + b*4096;
  int4 c0 = ((const int4*)h1)[threadIdx.x*4 + 0];
  int4 c1 = ((const int4*)h1)[threadIdx.x*4 + 1];
  int4 c2 = ((const int4*)h1)[threadIdx.x*4 + 2];
  int4 c3 = ((const int4*)h1)[threadIdx.x*4 + 3];
  int s = c0.x+c0.y+c0.z+c0.w + c1.x+c1.y+c1.z+c1.w
        + c2.x+c2.y+c2.z+c2.w + c3.x+c3.y+c3.z+c3.w;
  int sel0 = state[b*2];
  if (threadIdx.x == 0 && sel0 == 0) s += NPART;
  part[threadIdx.x] = s;
  __syncthreads();
  if (threadIdx.x == 0) {
    int r = state[b*2 + 1], cum = 0, ch = 0;
    for (; ch < 256; ++ch) { if (cum + part[ch] > r) break; cum += part[ch]; }
    int4 d0 = ((const int4*)h1)[ch*4 + 0];
    int4 d1 = ((const int4*)h1)[ch*4 + 1];
    int4 d2 = ((const int4*)h1)[ch*4 + 2];
    int4 d3 = ((const int4*)h1)[ch*4 + 3];
    int cc[16] = {d0.x,d0.y,d0.z,d0.w, d1.x,d1.y,d1.z,d1.w,
                  d2.x,d2.y,d2.z,d2.w, d3.x,d3.y,d3.z,d3.w};
    if (sel0 == 0 && ch == 0) cc[0] += NPART;
    int q = 0;
    for (;; ++q) { if (cum + cc[q] > r) break; cum += cc[q]; }
    int bin = ch*16 + q;
    // top 24 bits exact; low 8 -> midpoint (rel err <= 2^-16)
    unsigned mb = (((unsigned)sel0) << 20) | (((unsigned)bin) << 8) | 128u;
    float med = sqrtf(__uint_as_float(mb));
    float h = med * med / LOGN_F;
    shp[0] = -1.0f / h;
    shp[1] =  2.0f / h;
  }
  __syncthreads();
  float neginvh = shp[0];
  float two_h   = shp[1];

  int rbase = (blockIdx.x & 127)*16 + (threadIdx.x >> 6)*4;
  int lane = threadIdx.x & 63;
  const float4* xb = (const float4*)x + b*NPART;
  const float4* gb = (const float4*)g + b*NPART;
  float4 xi[4];
#pragma unroll
  for (int r = 0; r < 4; ++r) xi[r] = xb[rbase + r];
  float  S0[4] = {0.f, 0.f, 0.f, 0.f};
  float4 Sc[4] = {{0,0,0,0},{0,0,0,0},{0,0,0,0},{0,0,0,0}};

  // stage tile 0
  {
    float4 x0 = xb[threadIdx.x];
    float4 x1 = xb[256 + threadIdx.x];
    float4 g0 = gb[threadIdx.x];
    float4 g1 = gb[256 + threadIdx.x];
    sx[0][threadIdx.x]       = x0;
    sx[0][256 + threadIdx.x] = x1;
    sc[0][threadIdx.x]       = make_float4(fmaf(-two_h, x0.x, g0.x),
                                           fmaf(-two_h, x0.y, g0.y),
                                           fmaf(-two_h, x0.z, g0.z),
                                           fmaf(-two_h, x0.w, g0.w));
    sc[0][256 + threadIdx.x] = make_float4(fmaf(-two_h, x1.x, g1.x),
                                           fmaf(-two_h, x1.y, g1.y),
                                           fmaf(-two_h, x1.z, g1.z),
                                           fmaf(-two_h, x1.w, g1.w));
  }
  __syncthreads();
  for (int t = 0; t < 4; ++t) {
    int cur = t & 1, nxt = cur ^ 1;
    float4 nx0, nx1, ng0, ng1;
    if (t < 3) {                       // prefetch next tile (hidden)
      nx0 = xb[(t + 1)*512 + threadIdx.x];
      nx1 = xb[(t + 1)*512 + 256 + threadIdx.x];
      ng0 = gb[(t + 1)*512 + threadIdx.x];
      ng1 = gb[(t + 1)*512 + 256 + threadIdx.x];
    }
#pragma unroll
    for (int q = 0; q < 8; ++q) {
      float4 xj = sx[cur][lane + 64*q];
      float4 cj = sc[cur][lane + 64*q];
#pragma unroll
      for (int r = 0; r < 4; ++r) {
        float dx = xi[r].x - xj.x, dy = xi[r].y - xj.y;
        float dz = xi[r].z - xj.z, dw = xi[r].w - xj.w;
        float sq = fmaf(dx, dx, fmaf(dy, dy, fmaf(dz, dz, dw*dw)));
        float e = __expf(sq * neginvh);
        S0[r] += e;
        Sc[r].x = fmaf(e, cj.x, Sc[r].x);
        Sc[r].y = fmaf(e, cj.y, Sc[r].y);
        Sc[r].z = fmaf(e, cj.z, Sc[r].z);
        Sc[r].w = fmaf(e, cj.w, Sc[r].w);
      }
    }
    __syncthreads();
    if (t < 3) {
      sx[nxt][threadIdx.x]       = nx0;
      sx[nxt][256 + threadIdx.x] = nx1;
      sc[nxt][threadIdx.x]       = make_float4(fmaf(-two_h, nx0.x, ng0.x),
                                               fmaf(-two_h, nx0.y, ng0.y),
                                               fmaf(-two_h, nx0.z, ng0.z),
                                               fmaf(-two_h, nx0.w, ng0.w));
      sc[nxt][256 + threadIdx.x] = make_float4(fmaf(-two_h, nx1.x, ng1.x),
                                               fmaf(-two_h, nx1.y, ng1.y),
                                               fmaf(-two_h, nx1.z, ng1.z),
                                               fmaf(-two_h, nx1.w, ng1.w));
      __syncthreads();
    }
  }

#pragma unroll
  for (int d = 1; d < 64; d <<= 1) {
#pragma unroll
    for (int r = 0; r < 4; ++r) {
      S0[r]   += __shfl_xor(S0[r], d);
      Sc[r].x += __shfl_xor(Sc[r].x, d);
      Sc[r].y += __shfl_xor(Sc[r].y, d);
      Sc[r].z += __shfl_xor(Sc[r].z, d);
      Sc[r].w += __shfl_xor(Sc[r].w, d);
    }
  }
  if (lane == 0) {
    const float invN = 1.0f / 2048.0f;
#pragma unroll
    for (int r = 0; r < 4; ++r) {
      int row = rbase + r;
      float th0 = two_h * S0[r];
      float4 sv;
      sv.x = fmaf(th0, xi[r].x, Sc[r].x) * invN;
      sv.y = fmaf(th0, xi[r].y, Sc[r].y) * invN;
      sv.z = fmaf(th0, xi[r].z, Sc[r].z) * invN;
      sv.w = fmaf(th0, xi[r].w, Sc[r].w) * invN;
      float4 st;
      if (MODE == 0) {
        st = make_float4(0.1f*sv.x*sv.x, 0.1f*sv.y*sv.y,
                         0.1f*sv.z*sv.z, 0.1f*sv.w*sv.w);
      } else {
        st = ((float4*)stepb)[b*NPART + row];
        st.x = 0.9f*st.x + 0.1f*sv.x*sv.x;
        st.y = 0.9f*st.y + 0.1f*sv.y*sv.y;
        st.z = 0.9f*st.z + 0.1f*sv.z*sv.z;
        st.w = 0.9f*st.w + 0.1f*sv.w*sv.w;
      }
      float4 xn;
      xn.x = xi[r].x + 0.1f*sv.x / (sqrtf(st.x) + 1e-8f);
      xn.y = xi[r].y + 0.1f*sv.y / (sqrtf(st.y) + 1e-8f);
      xn.z = xi[r].z + 0.1f*sv.z / (sqrtf(st.z) + 1e-8f);
      xn.w = xi[r].w + 0.1f*sv.w / (sqrtf(st.w) + 1e-8f);
      if (MODE != 2) {
        ((float4*)stepb)[b*NPART + row] = st;
        ((float4*)xout)[b*NPART + row] = xn;
      } else {
        float* o = outp + (size_t)(b*NPART + row) * 5;
        o[0] = xn.x; o[1] = xn.y; o[2] = xn.z; o[3] = xn.w;
        o[4] = -LOGN_F;
      }
    }
  }
}

extern "C" void kernel_launch(void* const* d_in, const int* in_sizes, int n_in,
                              void* d_out, int out_size, void* d_ws, size_t ws_size,
                              hipStream_t stream) {
  const float* prev  = (const float*)d_in[0];   // (8,2048,4)
  const float* obs   = (const float*)d_in[1];   // (8,4)
  const float* noise = (const float*)d_in[2];   // (8,2048,4)
  float* out = (float*)d_out;                   // (8,2048,5)

  float* ws = (float*)d_ws;
  float* xA    = ws;
  float* xB    = xA + 65536;
  float* gbuf  = xB + 65536;
  float* stepb = gbuf + 65536;
  float* apb   = stepb + 65536;
  int*   state = (int*)(apb + 65536);       // 16 ints
  int*   hist0 = state + 16;                // 8*2048 ints
  int*   hist1 = hist0 + 8*2048;            // 8*4096 ints

  k_init<<<64, 256, 0, stream>>>(prev, noise, xA, apb, hist0);

  float* xc = xA;
  float* xn = xB;
  for (int it = 0; it < 3; ++it) {
    k_s1<<<2048, 256, 0, stream>>>(xc, apb, obs, gbuf, hist0, hist1);
    k_s2<<<1024, 256, 0, stream>>>(xc, state, hist0, hist1);
    if (it == 0) {
      k_s3<0><<<1024, 256, 0, stream>>>(xc, gbuf, state, hist0, hist1, stepb, xn, nullptr);
    } else if (it == 1) {
      k_s3<1><<<1024, 256, 0, stream>>>(xc, gbuf, state, hist0, hist1, stepb, xn, nullptr);
    } else {
      k_s3<2><<<1024, 256, 0, stream>>>(xc, gbuf, state, hist0, hist1, stepb, nullptr, out);
    }
    float* t = xc; xc = xn; xn = t;
  }
}